// Round 1
// baseline (143.828 us; speedup 1.0000x reference)
//
#include <hip/hip_runtime.h>

typedef __attribute__((ext_vector_type(8))) short short8;
typedef __attribute__((ext_vector_type(4))) float floatx4;
typedef __attribute__((ext_vector_type(4))) unsigned short ushortx4;

#define MFMA_BF16(A, Bv, C) __builtin_amdgcn_mfma_f32_16x16x32_bf16(A, Bv, C, 0, 0, 0)

#if __has_builtin(__builtin_amdgcn_exp2f)
#define EXP2(x) __builtin_amdgcn_exp2f(x)
#else
#define EXP2(x) exp2f(x)
#endif

__device__ __forceinline__ unsigned short f2bf(float f) {
  unsigned int u = __builtin_bit_cast(unsigned int, f);
  u += 0x7FFFu + ((u >> 16) & 1u);  // RNE
  return (unsigned short)(u >> 16);
}

// Kernel 1: fp32->bf16; Q pre-scaled by (1/sqrt(64))*log2(e) so QK^T scores are log2-domain.
__global__ __launch_bounds__(256) void convert_qk(
    const float* __restrict__ q, const float* __restrict__ k,
    unsigned short* __restrict__ qb, unsigned short* __restrict__ kb) {
  int blk = blockIdx.x;
  const float* src;
  unsigned short* dst;
  float scale;
  if (blk < 512) { src = q; dst = qb; scale = 0.18033688011112042f; }
  else           { src = k; dst = kb; scale = 1.0f; blk -= 512; }
  size_t base = (size_t)blk * 4096 + threadIdx.x * 4;
#pragma unroll
  for (int i = 0; i < 4; i++) {
    size_t off = base + (size_t)i * 1024;
    floatx4 f = *(const floatx4*)(src + off);
    ushortx4 h;
    h[0] = f2bf(f[0] * scale);
    h[1] = f2bf(f[1] * scale);
    h[2] = f2bf(f[2] * scale);
    h[3] = f2bf(f[3] * scale);
    *(ushortx4*)(dst + off) = h;
  }
}

// Kernel 2: V [B][S][64] fp32 -> Vt [B][64][S] bf16 (LDS-tiled 64x64 transpose)
__global__ __launch_bounds__(256) void transpose_v(
    const float* __restrict__ v, unsigned short* __restrict__ vt) {
  __shared__ float tile[64 * 68];  // stride 68 keeps float4 16B-aligned + spreads banks
  int b = blockIdx.x >> 6, si = blockIdx.x & 63;
  int t = threadIdx.x;
  int r = t >> 2, c4 = (t & 3) * 16;
  const float* vp = v + ((size_t)b * 4096 + si * 64 + r) * 64 + c4;
#pragma unroll
  for (int i = 0; i < 4; i++)
    *(floatx4*)(tile + r * 68 + c4 + i * 4) = *(const floatx4*)(vp + i * 4);
  __syncthreads();
  // now r = d-row, c4 = s-chunk
  unsigned short* vo = vt + ((size_t)b * 64 + r) * 4096 + si * 64 + c4;
#pragma unroll
  for (int i = 0; i < 4; i++) {
    ushortx4 h;
#pragma unroll
    for (int j = 0; j < 4; j++) h[j] = f2bf(tile[(c4 + i * 4 + j) * 68 + r]);
    *(ushortx4*)(vo + i * 4) = h;
  }
}

// Main attention: block = 64 q-rows, 4 waves split keys (32/iter each), merge at end.
// No barriers in hot loop (P round-trip uses per-wave LDS region).
__global__ __launch_bounds__(256, 2) void attn(
    const unsigned short* __restrict__ qb, const unsigned short* __restrict__ kb,
    const unsigned short* __restrict__ vt, const float* __restrict__ mask,
    float* __restrict__ out) {
  __shared__ __align__(16) char smem[35328];  // loop: P 4x5120=20480; epilogue: 2*4352*4+512
  const int tid = threadIdx.x;
  const int wave = tid >> 6, lane = tid & 63;
  const int c = lane & 15, quad = lane >> 4;
  const int b = blockIdx.x & 7, qt = blockIdx.x >> 3;  // blk%8==b -> batch-per-XCD L2 locality
  const int q0 = qt * 64;

  const unsigned short* qB = qb + (size_t)b * 4096 * 64;
  const unsigned short* kB = kb + (size_t)b * 4096 * 64;
  const unsigned short* vB = vt + (size_t)b * 64 * 4096;

  // Q A-fragments: A[m=lane&15][k=quad*8+j], kept in regs for whole loop
  short8 qf[4][2];
#pragma unroll
  for (int mt = 0; mt < 4; mt++)
#pragma unroll
    for (int ks = 0; ks < 2; ks++)
      qf[mt][ks] = *(const short8*)(qB + (q0 + mt * 16 + c) * 64 + ks * 32 + quad * 8);

  floatx4 o[4][4], ol[4];
#pragma unroll
  for (int mt = 0; mt < 4; mt++) {
    ol[mt] = (floatx4){0.f, 0.f, 0.f, 0.f};
#pragma unroll
    for (int dt = 0; dt < 4; dt++) o[mt][dt] = (floatx4){0.f, 0.f, 0.f, 0.f};
  }

  short8 ones;  // all-ones B operand: every output column = row-sum (free l accumulation)
#pragma unroll
  for (int j = 0; j < 8; j++) ones[j] = (short)0x3F80;

  char* pbase = smem + wave * 5120;              // P region: [64 rows][stride 80B]
  char* pw = pbase + quad * 320 + c * 2;         // + mt*1280 + r*80 + nt*32
  const char* prd = pbase + c * 80 + quad * 16;  // + mt*1280 (b128 A-frag read)

  for (int t = wave; t < 128; t += 4) {
    const int key0 = t * 32;
    short8 kf[2][2], vf[4];
#pragma unroll
    for (int nt = 0; nt < 2; nt++)
#pragma unroll
      for (int ks = 0; ks < 2; ks++)
        kf[nt][ks] = *(const short8*)(kB + (key0 + nt * 16 + c) * 64 + ks * 32 + quad * 8);
#pragma unroll
    for (int dt = 0; dt < 4; dt++)
      vf[dt] = *(const short8*)(vB + (dt * 16 + c) * 4096 + key0 + quad * 8);

    // S = Q*K^T (log2-domain scores), then P = exp2(S) -> LDS (C-layout -> row-major)
#pragma unroll
    for (int mt = 0; mt < 4; mt++)
#pragma unroll
      for (int nt = 0; nt < 2; nt++) {
        floatx4 s = (floatx4){0.f, 0.f, 0.f, 0.f};
        s = MFMA_BF16(qf[mt][0], kf[nt][0], s);
        s = MFMA_BF16(qf[mt][1], kf[nt][1], s);
#pragma unroll
        for (int r = 0; r < 4; r++) {
          float p = EXP2(s[r]);
          *(unsigned short*)(pw + mt * 1280 + r * 80 + nt * 32) = f2bf(p);
        }
      }

    // O += P*V ; ol += P*ones (row sums). P read back in A-layout (b128).
#pragma unroll
    for (int mt = 0; mt < 4; mt++) {
      short8 pf = *(const short8*)(prd + mt * 1280);
#pragma unroll
      for (int dt = 0; dt < 4; dt++) o[mt][dt] = MFMA_BF16(pf, vf[dt], o[mt][dt]);
      ol[mt] = MFMA_BF16(pf, ones, ol[mt]);
    }
  }

  // Merge 4 wave-partials (plain sums -- no max offsets needed): 2 regions + RMW.
  __syncthreads();
  float* obuf = (float*)smem;            // [2][64][68]
  float* lbuf = (float*)(smem + 34816);  // [2][64]
  const int w2 = wave & 1;
  if (wave < 2) {
#pragma unroll
    for (int mt = 0; mt < 4; mt++) {
#pragma unroll
      for (int dt = 0; dt < 4; dt++)
#pragma unroll
        for (int r = 0; r < 4; r++)
          obuf[w2 * 4352 + (mt * 16 + quad * 4 + r) * 68 + dt * 16 + c] = o[mt][dt][r];
      if (c == 0)
#pragma unroll
        for (int r = 0; r < 4; r++)
          lbuf[w2 * 64 + mt * 16 + quad * 4 + r] = ol[mt][r];
    }
  }
  __syncthreads();
  if (wave >= 2) {
#pragma unroll
    for (int mt = 0; mt < 4; mt++) {
#pragma unroll
      for (int dt = 0; dt < 4; dt++)
#pragma unroll
        for (int r = 0; r < 4; r++)
          obuf[w2 * 4352 + (mt * 16 + quad * 4 + r) * 68 + dt * 16 + c] += o[mt][dt][r];
      if (c == 0)
#pragma unroll
        for (int r = 0; r < 4; r++)
          lbuf[w2 * 64 + mt * 16 + quad * 4 + r] += ol[mt][r];
    }
  }
  __syncthreads();

  // Final: out = (O0+O1)/l * mask, coalesced float4 stores
  const int row = tid >> 2, dg = (tid & 3) * 16;
  float l = lbuf[row] + lbuf[64 + row];
  float sc = mask[b * 4096 + q0 + row] / l;
  float* op = out + ((size_t)b * 4096 + q0 + row) * 64 + dg;
#pragma unroll
  for (int i = 0; i < 4; i++) {
    floatx4 a = *(const floatx4*)(obuf + row * 68 + dg + i * 4);
    floatx4 b2 = *(const floatx4*)(obuf + 4352 + row * 68 + dg + i * 4);
    floatx4 res = (a + b2) * sc;
    *(floatx4*)(op + i * 4) = res;
  }
}

extern "C" void kernel_launch(void* const* d_in, const int* in_sizes, int n_in,
                              void* d_out, int out_size, void* d_ws, size_t ws_size,
                              hipStream_t stream) {
  const float* q = (const float*)d_in[0];
  const float* k = (const float*)d_in[1];
  const float* v = (const float*)d_in[2];
  const float* mask = (const float*)d_in[3];
  unsigned short* qb = (unsigned short*)d_ws;          // 4 MB
  unsigned short* kb = qb + 8 * 4096 * 64;             // 4 MB
  unsigned short* vt = kb + 8 * 4096 * 64;             // 4 MB (needs ws >= 12 MB)
  convert_qk<<<1024, 256, 0, stream>>>(q, k, qb, kb);
  transpose_v<<<512, 256, 0, stream>>>(v, vt);
  attn<<<512, 256, 0, stream>>>(qb, kb, vt, mask, (float*)d_out);
}